// Round 2
// baseline (8456.872 us; speedup 1.0000x reference)
//
#include <hip/hip_runtime.h>
#include <hip/hip_bf16.h>
#include <cstddef>

#define B_    2
#define S_    2048
#define HID_  2048
#define NH_   8
#define NKV_  2
#define HD_   256
#define NREP_ (NH_ / NKV_)
#define EPS_  1e-6f

// ---------------- GEMM: C[M,N] = A[M,K] @ W[N,K]^T (both row-major) ----------------
#define BM 64
#define BN 64
#define BK 16

__global__ __launch_bounds__(256) void gemm_nt(const float* __restrict__ A,
                                               const float* __restrict__ W,
                                               float* __restrict__ C,
                                               int M, int N, int K) {
  __shared__ float As[BM][BK + 1];
  __shared__ float Bs[BN][BK + 1];
  const int bm = blockIdx.y * BM;
  const int bn = blockIdx.x * BN;
  const int tid = threadIdx.x;
  const int tr = (tid >> 4) << 2;   // 0..60
  const int tc = (tid & 15) << 2;   // 0..60
  // staging coords: one float4 per thread per tile
  const int lr = tid >> 2;          // 0..63
  const int lc = (tid & 3) << 2;    // 0,4,8,12
  float acc[4][4] = {};
  for (int k0 = 0; k0 < K; k0 += BK) {
    {
      const float4 a4 = *reinterpret_cast<const float4*>(&A[(size_t)(bm + lr) * K + k0 + lc]);
      const float4 b4 = *reinterpret_cast<const float4*>(&W[(size_t)(bn + lr) * K + k0 + lc]);
      As[lr][lc + 0] = a4.x; As[lr][lc + 1] = a4.y; As[lr][lc + 2] = a4.z; As[lr][lc + 3] = a4.w;
      Bs[lr][lc + 0] = b4.x; Bs[lr][lc + 1] = b4.y; Bs[lr][lc + 2] = b4.z; Bs[lr][lc + 3] = b4.w;
    }
    __syncthreads();
#pragma unroll
    for (int kk = 0; kk < BK; ++kk) {
      float a[4], b[4];
#pragma unroll
      for (int i = 0; i < 4; ++i) a[i] = As[tr + i][kk];
#pragma unroll
      for (int j = 0; j < 4; ++j) b[j] = Bs[tc + j][kk];
#pragma unroll
      for (int i = 0; i < 4; ++i)
#pragma unroll
        for (int j = 0; j < 4; ++j) acc[i][j] += a[i] * b[j];
    }
    __syncthreads();
  }
#pragma unroll
  for (int i = 0; i < 4; ++i)
#pragma unroll
    for (int j = 0; j < 4; ++j)
      C[(size_t)(bm + tr + i) * N + bn + tc + j] = acc[i][j];
}

// ---------------- per-(b,s,h) LayerNorm (+ optional RoPE) ----------------
// in layout  : (B, S, nheads, HD)   (i.e. projection output rows)
// out layout : (B, nheads, S, HD)   (attention-friendly)
__global__ __launch_bounds__(256) void ln_rope(const float* __restrict__ in,
                                               float* __restrict__ out,
                                               const float* __restrict__ w,
                                               const float* __restrict__ cos_t,
                                               const float* __restrict__ sin_t,
                                               int nheads, int do_rope) {
  const int blk = blockIdx.x;                 // (b*S + s)*nheads + h
  const int h = blk % nheads;
  const int s = (blk / nheads) % S_;
  const int b = blk / (nheads * S_);
  const int d = threadIdx.x;                  // 0..255 == HD
  __shared__ float red[256];
  __shared__ float ybuf[256];

  const float x = in[(size_t)blk * HD_ + d];

  red[d] = x;
  __syncthreads();
#pragma unroll
  for (int off = 128; off > 0; off >>= 1) {
    if (d < off) red[d] += red[d + off];
    __syncthreads();
  }
  const float mean = red[0] * (1.0f / HD_);
  __syncthreads();

  const float xc = x - mean;
  red[d] = xc * xc;
  __syncthreads();
#pragma unroll
  for (int off = 128; off > 0; off >>= 1) {
    if (d < off) red[d] += red[d + off];
    __syncthreads();
  }
  const float var = red[0] * (1.0f / HD_);

  const float wd = w ? w[d] : 1.0f;
  const float y = xc * rsqrtf(var + EPS_) * wd;

  float o;
  if (do_rope) {
    ybuf[d] = y;
    __syncthreads();
    const float rot = (d < HD_ / 2) ? -ybuf[d + HD_ / 2] : ybuf[d - HD_ / 2];
    const size_t cidx = ((size_t)b * S_ + s) * HD_ + d;
    o = y * cos_t[cidx] + rot * sin_t[cidx];
  } else {
    o = y;
  }
  out[(((size_t)b * nheads + h) * S_ + s) * HD_ + d] = o;
}

// ---------------- causal GQA attention, one block per (b,h,query-row) ----------------
// Q: (B, NH, S, HD), K/V: (B, NKV, S, HD), O: (B, S, NH*HD)
__global__ __launch_bounds__(256) void attn_row(const float* __restrict__ Q,
                                                const float* __restrict__ Kt,
                                                const float* __restrict__ Vt,
                                                float* __restrict__ O) {
  const int blk = blockIdx.x;                 // (b*NH + h)*S + sq
  const int sq = blk % S_;
  const int h = (blk / S_) % NH_;
  const int b = blk / (S_ * NH_);
  const int kvh = h / NREP_;
  const int tid = threadIdx.x;

  __shared__ float qs[HD_];
  __shared__ float ss[S_];
  __shared__ float red[256];

  const float* qrow = Q + (((size_t)b * NH_ + h) * S_ + sq) * HD_;
  qs[tid] = qrow[tid];
  __syncthreads();

  const int nk = sq + 1;                      // causal: keys 0..sq inclusive
  const float* Kbase = Kt + ((size_t)b * NKV_ + kvh) * S_ * HD_;
  for (int j = tid; j < nk; j += 256) {
    const float* krow = Kbase + (size_t)j * HD_;
    float acc = 0.0f;
#pragma unroll
    for (int dd = 0; dd < HD_; dd += 4) {
      const float4 q4 = *reinterpret_cast<const float4*>(&qs[dd]);
      const float4 k4 = *reinterpret_cast<const float4*>(&krow[dd]);
      acc += q4.x * k4.x + q4.y * k4.y + q4.z * k4.z + q4.w * k4.w;
    }
    ss[j] = acc;
  }
  __syncthreads();

  // row max
  float m = -1e30f;
  for (int j = tid; j < nk; j += 256) m = fmaxf(m, ss[j]);
  red[tid] = m;
  __syncthreads();
#pragma unroll
  for (int off = 128; off > 0; off >>= 1) {
    if (tid < off) red[tid] = fmaxf(red[tid], red[tid + off]);
    __syncthreads();
  }
  m = red[0];
  __syncthreads();

  // exp + sum
  float ssum = 0.0f;
  for (int j = tid; j < nk; j += 256) {
    const float p = expf(ss[j] - m);
    ss[j] = p;
    ssum += p;
  }
  red[tid] = ssum;
  __syncthreads();
#pragma unroll
  for (int off = 128; off > 0; off >>= 1) {
    if (tid < off) red[tid] += red[tid + off];
    __syncthreads();
  }
  const float inv = 1.0f / red[0];
  __syncthreads();

  // PV: each thread owns one output dim
  const float* Vbase = Vt + ((size_t)b * NKV_ + kvh) * S_ * HD_;
  float acc = 0.0f;
  for (int j = 0; j < nk; ++j) acc += ss[j] * Vbase[(size_t)j * HD_ + tid];

  O[((size_t)b * S_ + sq) * (NH_ * HD_) + (size_t)h * HD_ + tid] = acc * inv;
}

// ---------------- launch ----------------
extern "C" void kernel_launch(void* const* d_in, const int* in_sizes, int n_in,
                              void* d_out, int out_size, void* d_ws, size_t ws_size,
                              hipStream_t stream) {
  const float* hidden   = (const float*)d_in[0];
  const float* cos_t    = (const float*)d_in[1];
  const float* sin_t    = (const float*)d_in[2];
  // d_in[3] attention_mask: pure causal, applied analytically
  const float* q_w      = (const float*)d_in[4];
  const float* k_w      = (const float*)d_in[5];
  const float* v_w      = (const float*)d_in[6];
  const float* o_w      = (const float*)d_in[7];
  const float* q_norm_w = (const float*)d_in[8];
  const float* k_norm_w = (const float*)d_in[9];
  float* out = (float*)d_out;

  float* ws = (float*)d_ws;
  const size_t SZ_Q = (size_t)B_ * S_ * NH_ * HD_;    // 8388608
  const size_t SZ_K = (size_t)B_ * S_ * NKV_ * HD_;   // 2097152
  float* q_proj = ws;                                 // later reused as attn_out
  float* k_proj = q_proj + SZ_Q;
  float* v_proj = k_proj + SZ_K;
  float* q_rot  = v_proj + SZ_K;
  float* k_rot  = q_rot + SZ_Q;
  float* v_ln   = k_rot + SZ_K;
  // total: 25,165,824 floats = 96 MiB

  const int M = B_ * S_;  // 4096

  gemm_nt<<<dim3((NH_ * HD_) / BN, M / BM), 256, 0, stream>>>(hidden, q_w, q_proj, M, NH_ * HD_, HID_);
  gemm_nt<<<dim3((NKV_ * HD_) / BN, M / BM), 256, 0, stream>>>(hidden, k_w, k_proj, M, NKV_ * HD_, HID_);
  gemm_nt<<<dim3((NKV_ * HD_) / BN, M / BM), 256, 0, stream>>>(hidden, v_w, v_proj, M, NKV_ * HD_, HID_);

  ln_rope<<<M * NH_, 256, 0, stream>>>(q_proj, q_rot, q_norm_w, cos_t, sin_t, NH_, 1);
  ln_rope<<<M * NKV_, 256, 0, stream>>>(k_proj, k_rot, k_norm_w, cos_t, sin_t, NKV_, 1);
  ln_rope<<<M * NKV_, 256, 0, stream>>>(v_proj, v_ln, nullptr, cos_t, sin_t, NKV_, 0);

  float* attn_out = q_proj;  // q_proj no longer needed
  attn_row<<<B_ * NH_ * S_, 256, 0, stream>>>(q_rot, k_rot, v_ln, attn_out);

  gemm_nt<<<dim3(HID_ / BN, M / BM), 256, 0, stream>>>(attn_out, o_w, out, M, HID_, HID_);
}

// Round 4
// 2363.174 us; speedup vs baseline: 3.5786x; 3.5786x over previous
//
#include <hip/hip_runtime.h>
#include <hip/hip_bf16.h>
#include <cstddef>

#define B_    2
#define S_    2048
#define HID_  2048
#define NH_   8
#define NKV_  2
#define HD_   256
#define NREP_ (NH_ / NKV_)
#define EPS_  1e-6f

#define QBLK 64
#define KBLK 32

typedef short bf16x8 __attribute__((ext_vector_type(8)));
typedef float f32x4 __attribute__((ext_vector_type(4)));

static __device__ __forceinline__ ushort f2bf(float x) {
  uint u = __float_as_uint(x);
  return (ushort)((u + 0x7FFFu + ((u >> 16) & 1u)) >> 16);
}
static __device__ __forceinline__ float bf2f(ushort h) {
  return __uint_as_float(((uint)h) << 16);
}

// ---------------- GEMM: C[M,N] = A[M,K] @ W[N,K]^T (fp32, unchanged) ----------------
#define BM 64
#define BN 64
#define BK 16

__global__ __launch_bounds__(256) void gemm_nt(const float* __restrict__ A,
                                               const float* __restrict__ W,
                                               float* __restrict__ C,
                                               int M, int N, int K) {
  __shared__ float As[BM][BK + 1];
  __shared__ float Bs[BN][BK + 1];
  const int bm = blockIdx.y * BM;
  const int bn = blockIdx.x * BN;
  const int tid = threadIdx.x;
  const int tr = (tid >> 4) << 2;
  const int tc = (tid & 15) << 2;
  const int lr = tid >> 2;
  const int lc = (tid & 3) << 2;
  float acc[4][4] = {};
  for (int k0 = 0; k0 < K; k0 += BK) {
    {
      const float4 a4 = *reinterpret_cast<const float4*>(&A[(size_t)(bm + lr) * K + k0 + lc]);
      const float4 b4 = *reinterpret_cast<const float4*>(&W[(size_t)(bn + lr) * K + k0 + lc]);
      As[lr][lc + 0] = a4.x; As[lr][lc + 1] = a4.y; As[lr][lc + 2] = a4.z; As[lr][lc + 3] = a4.w;
      Bs[lr][lc + 0] = b4.x; Bs[lr][lc + 1] = b4.y; Bs[lr][lc + 2] = b4.z; Bs[lr][lc + 3] = b4.w;
    }
    __syncthreads();
#pragma unroll
    for (int kk = 0; kk < BK; ++kk) {
      float a[4], b[4];
#pragma unroll
      for (int i = 0; i < 4; ++i) a[i] = As[tr + i][kk];
#pragma unroll
      for (int j = 0; j < 4; ++j) b[j] = Bs[tc + j][kk];
#pragma unroll
      for (int i = 0; i < 4; ++i)
#pragma unroll
        for (int j = 0; j < 4; ++j) acc[i][j] += a[i] * b[j];
    }
    __syncthreads();
  }
#pragma unroll
  for (int i = 0; i < 4; ++i)
#pragma unroll
    for (int j = 0; j < 4; ++j)
      C[(size_t)(bm + tr + i) * N + bn + tc + j] = acc[i][j];
}

// ---------------- per-(b,s,h) LayerNorm (+ optional RoPE), split bf16 output ----------------
// in : (B, S, nheads, HD) fp32 ; out : (B, nheads, S, HD) bf16 hi (+ optional lo residual)
__global__ __launch_bounds__(256) void ln_rope(const float* __restrict__ in,
                                               ushort* __restrict__ out_hi,
                                               ushort* __restrict__ out_lo,
                                               const float* __restrict__ w,
                                               const float* __restrict__ cos_t,
                                               const float* __restrict__ sin_t,
                                               int nheads, int do_rope) {
  const int blk = blockIdx.x;
  const int h = blk % nheads;
  const int s = (blk / nheads) % S_;
  const int b = blk / (nheads * S_);
  const int d = threadIdx.x;
  __shared__ float red[256];
  __shared__ float ybuf[256];

  const float x = in[(size_t)blk * HD_ + d];

  red[d] = x;
  __syncthreads();
#pragma unroll
  for (int off = 128; off > 0; off >>= 1) {
    if (d < off) red[d] += red[d + off];
    __syncthreads();
  }
  const float mean = red[0] * (1.0f / HD_);
  __syncthreads();

  const float xc = x - mean;
  red[d] = xc * xc;
  __syncthreads();
#pragma unroll
  for (int off = 128; off > 0; off >>= 1) {
    if (d < off) red[d] += red[d + off];
    __syncthreads();
  }
  const float var = red[0] * (1.0f / HD_);

  const float wd = w ? w[d] : 1.0f;
  const float y = xc * rsqrtf(var + EPS_) * wd;

  float o;
  if (do_rope) {
    ybuf[d] = y;
    __syncthreads();
    const float rot = (d < HD_ / 2) ? -ybuf[d + HD_ / 2] : ybuf[d - HD_ / 2];
    const size_t cidx = ((size_t)b * S_ + s) * HD_ + d;
    o = y * cos_t[cidx] + rot * sin_t[cidx];
  } else {
    o = y;
  }
  const size_t oidx = (((size_t)b * nheads + h) * S_ + s) * HD_ + d;
  const ushort hi = f2bf(o);
  out_hi[oidx] = hi;
  if (out_lo) out_lo[oidx] = f2bf(o - bf2f(hi));
}

// ---------------- MFMA flash attention, split-precision QK^T ----------------
// Qh/Ql: (B,NH,S,256) bf16 ; Kh/Kl,V: (B,NKV,S,256) bf16 ; O: (B,S,NH*256) fp32
// block = 64 q-rows x one (b,h); 4 waves x 16 rows; KV tiles of 32.
// S = Qh*Kh + Ql*Kh + Qh*Kl  (Ql*Kl ~ 2^-18, dropped) -> fp32-accurate scores.
__global__ __launch_bounds__(256) void attn_mfma(const ushort* __restrict__ Qh,
                                                 const ushort* __restrict__ Ql,
                                                 const ushort* __restrict__ Kh,
                                                 const ushort* __restrict__ Kl,
                                                 const ushort* __restrict__ V,
                                                 float* __restrict__ O) {
  const int q0 = blockIdx.x * QBLK;
  const int h = blockIdx.y;
  const int b = blockIdx.z;
  const int kvh = h / NREP_;
  const int tid = threadIdx.x;
  const int wave = tid >> 6;
  const int lane = tid & 63;
  const int lrow = lane & 15;   // A-row / B-col index
  const int lgrp = lane >> 4;   // 0..3

  __shared__ ushort Ksh_h[KBLK * 256];   // 16 KB, XOR-swizzled rows of 512B
  __shared__ ushort Ksh_l[KBLK * 256];   // 16 KB
  __shared__ ushort Vsh[256 * 36];       // 18 KB, V^T padded (stride 36 elems = 72B)
  __shared__ ushort Psh[4][16][40];      // 5 KB, per-wave P tile

  // ---- Q fragments: 16 rows x 256 dims per wave, 8 chunks of K=32, hi+lo ----
  const size_t qoff = (((size_t)b * NH_ + h) * S_ + q0 + wave * 16 + lrow) * HD_;
  bf16x8 qf_h[8], qf_l[8];
#pragma unroll
  for (int c = 0; c < 8; ++c) {
    qf_h[c] = *reinterpret_cast<const bf16x8*>(Qh + qoff + c * 32 + lgrp * 8);
    qf_l[c] = *reinterpret_cast<const bf16x8*>(Ql + qoff + c * 32 + lgrp * 8);
  }

  f32x4 Oacc[16];
#pragma unroll
  for (int i = 0; i < 16; ++i) Oacc[i] = (f32x4){0.f, 0.f, 0.f, 0.f};
  float m_r[4] = {-3e38f, -3e38f, -3e38f, -3e38f};
  float l_r[4] = {0.f, 0.f, 0.f, 0.f};

  const ushort* Khp = Kh + ((size_t)b * NKV_ + kvh) * S_ * HD_;
  const ushort* Klp = Kl + ((size_t)b * NKV_ + kvh) * S_ * HD_;
  const ushort* Vp  = V  + ((size_t)b * NKV_ + kvh) * S_ * HD_;

  const int nt = q0 / KBLK + 2;  // tiles covering keys < q0+64
  const int vk = tid & 31;       // V staging: key row
  const int vg = tid >> 5;       // V staging: d-group 0..7

  for (int t = 0; t < nt; ++t) {
    const int k0 = t * KBLK;
    __syncthreads();  // prev tile fully consumed

    // ---- stage K tiles [32][256] bf16 (hi & lo), swizzled: byte ^= ((row&7)<<4) ----
#pragma unroll
    for (int p = 0; p < 4; ++p) {
      const int o = (tid << 4) + (p << 12);            // dest byte offset, 16KB total
      const int krow = o >> 9;
      const int so = o ^ ((krow & 7) << 4);
      *reinterpret_cast<uint4*>(reinterpret_cast<char*>(Ksh_h) + so) =
          *reinterpret_cast<const uint4*>(reinterpret_cast<const char*>(Khp) + (size_t)k0 * 512 + o);
      *reinterpret_cast<uint4*>(reinterpret_cast<char*>(Ksh_l) + so) =
          *reinterpret_cast<const uint4*>(reinterpret_cast<const char*>(Klp) + (size_t)k0 * 512 + o);
    }
    // ---- stage V^T tile: Vsh[d][k] = V[k0+k][d], padded stride 36 ----
#pragma unroll
    for (int p = 0; p < 4; ++p) {
      const int d0 = vg * 8 + p * 64;
      union { uint4 u4; ushort e[8]; } vv;
      vv.u4 = *reinterpret_cast<const uint4*>(Vp + (size_t)(k0 + vk) * HD_ + d0);
#pragma unroll
      for (int j = 0; j < 8; ++j) Vsh[(d0 + j) * 36 + vk] = vv.e[j];
    }
    __syncthreads();  // staging visible

    // ---- QK^T: S[16 q][32 k], 3-term split precision ----
    f32x4 s0 = (f32x4){0.f, 0.f, 0.f, 0.f};
    f32x4 s1 = (f32x4){0.f, 0.f, 0.f, 0.f};
#pragma unroll
    for (int c = 0; c < 8; ++c) {
      const int bc = c * 64 + lgrp * 16;  // byte col within K row
      const int r0 = lrow, r1 = 16 + lrow;
      const int o0 = r0 * 512 + (bc ^ ((r0 & 7) << 4));
      const int o1 = r1 * 512 + (bc ^ ((r1 & 7) << 4));
      bf16x8 kh0 = *reinterpret_cast<const bf16x8*>(reinterpret_cast<const char*>(Ksh_h) + o0);
      bf16x8 kh1 = *reinterpret_cast<const bf16x8*>(reinterpret_cast<const char*>(Ksh_h) + o1);
      bf16x8 kl0 = *reinterpret_cast<const bf16x8*>(reinterpret_cast<const char*>(Ksh_l) + o0);
      bf16x8 kl1 = *reinterpret_cast<const bf16x8*>(reinterpret_cast<const char*>(Ksh_l) + o1);
      s0 = __builtin_amdgcn_mfma_f32_16x16x32_bf16(qf_h[c], kh0, s0, 0, 0, 0);
      s0 = __builtin_amdgcn_mfma_f32_16x16x32_bf16(qf_l[c], kh0, s0, 0, 0, 0);
      s0 = __builtin_amdgcn_mfma_f32_16x16x32_bf16(qf_h[c], kl0, s0, 0, 0, 0);
      s1 = __builtin_amdgcn_mfma_f32_16x16x32_bf16(qf_h[c], kh1, s1, 0, 0, 0);
      s1 = __builtin_amdgcn_mfma_f32_16x16x32_bf16(qf_l[c], kh1, s1, 0, 0, 0);
      s1 = __builtin_amdgcn_mfma_f32_16x16x32_bf16(qf_h[c], kl1, s1, 0, 0, 0);
    }

    // ---- online softmax (per q-row; row = lgrp*4+reg, key-col = lrow) ----
    const int qg = q0 + wave * 16 + lgrp * 4;  // + reg = global q row
    float sc_r[4];
#pragma unroll
    for (int reg = 0; reg < 4; ++reg) {
      const int qrow = qg + reg;
      const bool ok0 = (k0 + lrow) <= qrow;
      const bool ok1 = (k0 + 16 + lrow) <= qrow;
      float v0 = ok0 ? s0[reg] : -3e38f;
      float v1 = ok1 ? s1[reg] : -3e38f;
      float mx = fmaxf(v0, v1);
      mx = fmaxf(mx, __shfl_xor(mx, 1));
      mx = fmaxf(mx, __shfl_xor(mx, 2));
      mx = fmaxf(mx, __shfl_xor(mx, 4));
      mx = fmaxf(mx, __shfl_xor(mx, 8));
      const float mnew = fmaxf(m_r[reg], mx);
      const float sc = expf(m_r[reg] - mnew);  // both -3e38 -> exp(0)=1; -inf-like -> 0
      const float p0 = ok0 ? expf(s0[reg] - mnew) : 0.f;
      const float p1 = ok1 ? expf(s1[reg] - mnew) : 0.f;
      float rs = p0 + p1;
      rs += __shfl_xor(rs, 1);
      rs += __shfl_xor(rs, 2);
      rs += __shfl_xor(rs, 4);
      rs += __shfl_xor(rs, 8);
      l_r[reg] = l_r[reg] * sc + rs;
      m_r[reg] = mnew;
      sc_r[reg] = sc;
      Psh[wave][lgrp * 4 + reg][lrow] = f2bf(p0);
      Psh[wave][lgrp * 4 + reg][16 + lrow] = f2bf(p1);
    }
    // rescale O accumulators
    const f32x4 scv = (f32x4){sc_r[0], sc_r[1], sc_r[2], sc_r[3]};
#pragma unroll
    for (int ch = 0; ch < 16; ++ch) Oacc[ch] *= scv;

    __syncthreads();  // P writes ordered before reads

    // ---- PV: O[16 q][256 d] += P[16 q][32 k] * V[32 k][256 d] ----
    bf16x8 pa = *reinterpret_cast<const bf16x8*>(&Psh[wave][lrow][lgrp * 8]);
#pragma unroll
    for (int ch = 0; ch < 16; ++ch) {
      const ushort* vp = &Vsh[(ch * 16 + lrow) * 36 + lgrp * 8];
      union { uint u[4]; bf16x8 v; } tmp;
      const uint2 lo = *reinterpret_cast<const uint2*>(vp);
      const uint2 hi = *reinterpret_cast<const uint2*>(vp + 4);
      tmp.u[0] = lo.x; tmp.u[1] = lo.y; tmp.u[2] = hi.x; tmp.u[3] = hi.y;
      Oacc[ch] = __builtin_amdgcn_mfma_f32_16x16x32_bf16(pa, tmp.v, Oacc[ch], 0, 0, 0);
    }
  }

  // ---- write out: O[b][q][h*256 + d], normalized ----
  float* obase = O + ((size_t)b * S_ + q0 + wave * 16) * (NH_ * HD_) + (size_t)h * HD_;
#pragma unroll
  for (int reg = 0; reg < 4; ++reg) {
    const float inv = 1.0f / l_r[reg];
    float* orow = obase + (size_t)(lgrp * 4 + reg) * (NH_ * HD_);
#pragma unroll
    for (int ch = 0; ch < 16; ++ch)
      orow[ch * 16 + lrow] = Oacc[ch][reg] * inv;
  }
}

// ---------------- launch ----------------
extern "C" void kernel_launch(void* const* d_in, const int* in_sizes, int n_in,
                              void* d_out, int out_size, void* d_ws, size_t ws_size,
                              hipStream_t stream) {
  const float* hidden   = (const float*)d_in[0];
  const float* cos_t    = (const float*)d_in[1];
  const float* sin_t    = (const float*)d_in[2];
  // d_in[3] attention_mask: pure causal, applied analytically
  const float* q_w      = (const float*)d_in[4];
  const float* k_w      = (const float*)d_in[5];
  const float* v_w      = (const float*)d_in[6];
  const float* o_w      = (const float*)d_in[7];
  const float* q_norm_w = (const float*)d_in[8];
  const float* k_norm_w = (const float*)d_in[9];
  float* out = (float*)d_out;

  float* ws = (float*)d_ws;
  const size_t SZ_Q = (size_t)B_ * S_ * NH_ * HD_;    // 8388608
  const size_t SZ_K = (size_t)B_ * S_ * NKV_ * HD_;   // 2097152
  float* q_proj = ws;                                 // fp32, later reused as attn_out
  float* k_proj = q_proj + SZ_Q;
  float* v_proj = k_proj + SZ_K;
  ushort* q_hi = (ushort*)(v_proj + SZ_K);
  ushort* q_lo = q_hi + SZ_Q;
  ushort* k_hi = q_lo + SZ_Q;
  ushort* k_lo = k_hi + SZ_K;
  ushort* v_bf = k_lo + SZ_K;
  // total: ~92.0 MiB

  const int M = B_ * S_;  // 4096

  gemm_nt<<<dim3((NH_ * HD_) / BN, M / BM), 256, 0, stream>>>(hidden, q_w, q_proj, M, NH_ * HD_, HID_);
  gemm_nt<<<dim3((NKV_ * HD_) / BN, M / BM), 256, 0, stream>>>(hidden, k_w, k_proj, M, NKV_ * HD_, HID_);
  gemm_nt<<<dim3((NKV_ * HD_) / BN, M / BM), 256, 0, stream>>>(hidden, v_w, v_proj, M, NKV_ * HD_, HID_);

  ln_rope<<<M * NH_, 256, 0, stream>>>(q_proj, q_hi, q_lo, q_norm_w, cos_t, sin_t, NH_, 1);
  ln_rope<<<M * NKV_, 256, 0, stream>>>(k_proj, k_hi, k_lo, k_norm_w, cos_t, sin_t, NKV_, 1);
  ln_rope<<<M * NKV_, 256, 0, stream>>>(v_proj, v_bf, nullptr, nullptr, cos_t, sin_t, NKV_, 0);

  float* attn_out = q_proj;  // q_proj consumed by ln_rope; reuse
  attn_mfma<<<dim3(S_ / QBLK, NH_, B_), 256, 0, stream>>>(q_hi, q_lo, k_hi, k_lo, v_bf, attn_out);

  gemm_nt<<<dim3(HID_ / BN, M / BM), 256, 0, stream>>>(attn_out, o_w, out, M, HID_, HID_);
}

// Round 6
// 1358.746 us; speedup vs baseline: 6.2240x; 1.7392x over previous
//
#include <hip/hip_runtime.h>
#include <hip/hip_bf16.h>
#include <cstddef>
#include <cstdint>

#define B_    2
#define S_    2048
#define HID_  2048
#define NH_   8
#define NKV_  2
#define HD_   256
#define NREP_ (NH_ / NKV_)
#define EPS_  1e-6f

#define QBLK 64
#define KBLK 32

typedef short bf16x8 __attribute__((ext_vector_type(8)));
typedef float f32x4 __attribute__((ext_vector_type(4)));

static __device__ __forceinline__ ushort f2bf(float x) {
  uint u = __float_as_uint(x);
  return (ushort)((u + 0x7FFFu + ((u >> 16) & 1u)) >> 16);
}
static __device__ __forceinline__ float bf2f(ushort h) {
  return __uint_as_float(((uint)h) << 16);
}

// async global->LDS, 16B per lane; LDS dest must be wave-uniform (HW adds lane*16)
static __device__ __forceinline__ void gload16(const void* g, void* l) {
  __builtin_amdgcn_global_load_lds(
      (const __attribute__((address_space(1))) uint*)g,
      (__attribute__((address_space(3))) uint*)l, 16, 0, 0);
}

// ---------------- fp32 -> bf16 hi (+ optional lo residual) ----------------
__global__ __launch_bounds__(256) void conv_split(const float* __restrict__ in,
                                                  ushort* __restrict__ hi,
                                                  ushort* __restrict__ lo,
                                                  int n4) {
  int i = blockIdx.x * 256 + threadIdx.x;
  const int stride = gridDim.x * 256;
  for (; i < n4; i += stride) {
    const float4 x = reinterpret_cast<const float4*>(in)[i];
    ushort4 h;
    h.x = f2bf(x.x); h.y = f2bf(x.y); h.z = f2bf(x.z); h.w = f2bf(x.w);
    reinterpret_cast<ushort4*>(hi)[i] = h;
    if (lo) {
      ushort4 l;
      l.x = f2bf(x.x - bf2f(h.x)); l.y = f2bf(x.y - bf2f(h.y));
      l.z = f2bf(x.z - bf2f(h.z)); l.w = f2bf(x.w - bf2f(h.w));
      reinterpret_cast<ushort4*>(lo)[i] = l;
    }
  }
}

// ---------------- bf16 MFMA GEMM: C[M,N] = A[M,K] @ W[N,K]^T ----------------
// SPLIT: C = Ah*Wh + Al*Wh + Ah*Wl (fp32-accurate). 128x128 tile, 4 waves (2x2),
// LDS layout [kc=4][128 rows][8 bf16] staged via global_load_lds (per-lane global src).
template <int SPLIT>
__global__ __launch_bounds__(256) void gemm_mfma(const ushort* __restrict__ Ah,
                                                 const ushort* __restrict__ Al,
                                                 const ushort* __restrict__ Wh,
                                                 const ushort* __restrict__ Wl,
                                                 float* __restrict__ C,
                                                 int M, int N, int K) {
  __shared__ __align__(16) ushort AshH[4096];
  __shared__ __align__(16) ushort BshH[4096];
  __shared__ __align__(16) ushort AshL[SPLIT ? 4096 : 8];
  __shared__ __align__(16) ushort BshL[SPLIT ? 4096 : 8];

  const int bm = blockIdx.y * 128;
  const int bn = blockIdx.x * 128;
  const int tid = threadIdx.x;
  const int wave = tid >> 6;
  const int lane = tid & 63;
  const int wr = wave >> 1;      // wave row 0..1 (64-row strip)
  const int wc = wave & 1;       // wave col 0..1 (64-col strip)
  const int lrow = lane & 15;
  const int lgrp = lane >> 4;    // k-chunk 0..3

  f32x4 acc[4][4];
#pragma unroll
  for (int m = 0; m < 4; ++m)
#pragma unroll
    for (int n = 0; n < 4; ++n) acc[m][n] = (f32x4){0.f, 0.f, 0.f, 0.f};

  for (int k0 = 0; k0 < K; k0 += 32) {
    __syncthreads();  // prev compute done before overwrite
    // stage: 8 segments per tile (kc 0..3 x rowblock 0..1); each wave does 2
#pragma unroll
    for (int s = 0; s < 2; ++s) {
      const int seg = wave * 2 + s;
      const int kc = seg >> 1;
      const int rb = (seg & 1) * 64;
      const size_t gofs = (size_t)(bm + rb + lane) * K + k0 + kc * 8;
      const size_t gofsB = (size_t)(bn + rb + lane) * K + k0 + kc * 8;
      const int lofs = (kc * 128 + rb) * 16;  // bytes
      gload16(Ah + gofs, (char*)AshH + lofs);
      gload16(Wh + gofsB, (char*)BshH + lofs);
      if constexpr (SPLIT) {
        gload16(Al + gofs, (char*)AshL + lofs);
        gload16(Wl + gofsB, (char*)BshL + lofs);
      }
    }
    __syncthreads();  // staging visible (compiler drains vmcnt before barrier)

    bf16x8 af[4], bfr[4], afl[4], bfl[4];
#pragma unroll
    for (int m = 0; m < 4; ++m) {
      const int r = wr * 64 + m * 16 + lrow;
      af[m] = *reinterpret_cast<const bf16x8*>((const char*)AshH + (lgrp * 128 + r) * 16);
      if constexpr (SPLIT)
        afl[m] = *reinterpret_cast<const bf16x8*>((const char*)AshL + (lgrp * 128 + r) * 16);
    }
#pragma unroll
    for (int n = 0; n < 4; ++n) {
      const int c = wc * 64 + n * 16 + lrow;
      bfr[n] = *reinterpret_cast<const bf16x8*>((const char*)BshH + (lgrp * 128 + c) * 16);
      if constexpr (SPLIT)
        bfl[n] = *reinterpret_cast<const bf16x8*>((const char*)BshL + (lgrp * 128 + c) * 16);
    }
#pragma unroll
    for (int m = 0; m < 4; ++m)
#pragma unroll
      for (int n = 0; n < 4; ++n) {
        acc[m][n] = __builtin_amdgcn_mfma_f32_16x16x32_bf16(af[m], bfr[n], acc[m][n], 0, 0, 0);
        if constexpr (SPLIT) {
          acc[m][n] = __builtin_amdgcn_mfma_f32_16x16x32_bf16(afl[m], bfr[n], acc[m][n], 0, 0, 0);
          acc[m][n] = __builtin_amdgcn_mfma_f32_16x16x32_bf16(af[m], bfl[n], acc[m][n], 0, 0, 0);
        }
      }
  }

  // epilogue: C/D layout col=lane&15, row=(lane>>4)*4+reg
#pragma unroll
  for (int m = 0; m < 4; ++m) {
    const int row0 = bm + wr * 64 + m * 16 + lgrp * 4;
#pragma unroll
    for (int n = 0; n < 4; ++n) {
      const int col = bn + wc * 64 + n * 16 + lrow;
#pragma unroll
      for (int reg = 0; reg < 4; ++reg)
        C[(size_t)(row0 + reg) * N + col] = acc[m][n][reg];
    }
  }
}

// ---------------- in-place LayerNorm (+RoPE), fp32 row -> [hi 256 | lo 256] ushorts ----------------
__global__ __launch_bounds__(256) void ln_rope_ip(float* __restrict__ io,
                                                  const float* __restrict__ w,
                                                  const float* __restrict__ cos_t,
                                                  const float* __restrict__ sin_t,
                                                  int nheads, int do_rope, int do_split) {
  const int blk = blockIdx.x;  // (b*S+s)*nheads + h
  const int s = (blk / nheads) % S_;
  const int b = blk / (nheads * S_);
  const int d = threadIdx.x;
  __shared__ float red[256];
  __shared__ float ybuf[256];

  const float x = io[(size_t)blk * HD_ + d];

  red[d] = x;
  __syncthreads();
#pragma unroll
  for (int off = 128; off > 0; off >>= 1) {
    if (d < off) red[d] += red[d + off];
    __syncthreads();
  }
  const float mean = red[0] * (1.0f / HD_);
  __syncthreads();

  const float xc = x - mean;
  red[d] = xc * xc;
  __syncthreads();
#pragma unroll
  for (int off = 128; off > 0; off >>= 1) {
    if (d < off) red[d] += red[d + off];
    __syncthreads();
  }
  const float var = red[0] * (1.0f / HD_);

  const float wd = w ? w[d] : 1.0f;
  const float y = xc * rsqrtf(var + EPS_) * wd;

  float o;
  if (do_rope) {
    ybuf[d] = y;
    __syncthreads();
    const float rot = (d < HD_ / 2) ? -ybuf[d + HD_ / 2] : ybuf[d - HD_ / 2];
    const size_t cidx = ((size_t)b * S_ + s) * HD_ + d;
    o = y * cos_t[cidx] + rot * sin_t[cidx];
  } else {
    o = y;
  }
  // in-place: all global reads of this row happened before the first barrier
  ushort* us = reinterpret_cast<ushort*>(io);
  const ushort hi = f2bf(o);
  us[(size_t)blk * 512 + d] = hi;
  if (do_split) us[(size_t)blk * 512 + 256 + d] = f2bf(o - bf2f(hi));
}

// ---------------- MFMA flash attention, split-precision QK^T ----------------
// Q rows: packed [hi 256 | lo 256] at ((b*S+s)*NH+h)*512 ; K same with NKV; V hi-only.
// O written as bf16 (B,S,NH*HD) for the o-projection.
__global__ __launch_bounds__(256) void attn_mfma(const ushort* __restrict__ Q,
                                                 const ushort* __restrict__ K,
                                                 const ushort* __restrict__ V,
                                                 ushort* __restrict__ O) {
  const int q0 = blockIdx.x * QBLK;
  const int h = blockIdx.y;
  const int b = blockIdx.z;
  const int kvh = h / NREP_;
  const int tid = threadIdx.x;
  const int wave = tid >> 6;
  const int lane = tid & 63;
  const int lrow = lane & 15;
  const int lgrp = lane >> 4;

  __shared__ ushort Ksh_h[KBLK * 256];   // 16 KB, XOR-swizzled rows of 512B
  __shared__ ushort Ksh_l[KBLK * 256];   // 16 KB
  __shared__ ushort Vsh[256 * 36];       // 18 KB, V^T padded
  __shared__ ushort Psh[4][16][40];      // 5 KB

  // Q fragments (hi+lo), 16 rows per wave
  const ushort* Qrow = Q + (((size_t)b * S_ + q0 + wave * 16 + lrow) * NH_ + h) * 512;
  bf16x8 qf_h[8], qf_l[8];
#pragma unroll
  for (int c = 0; c < 8; ++c) {
    qf_h[c] = *reinterpret_cast<const bf16x8*>(Qrow + c * 32 + lgrp * 8);
    qf_l[c] = *reinterpret_cast<const bf16x8*>(Qrow + 256 + c * 32 + lgrp * 8);
  }

  f32x4 Oacc[16];
#pragma unroll
  for (int i = 0; i < 16; ++i) Oacc[i] = (f32x4){0.f, 0.f, 0.f, 0.f};
  float m_r[4] = {-3e38f, -3e38f, -3e38f, -3e38f};
  float l_r[4] = {0.f, 0.f, 0.f, 0.f};

  const char* Kbytes = reinterpret_cast<const char*>(K);
  const char* Vbytes = reinterpret_cast<const char*>(V);

  const int nt = q0 / KBLK + 2;
  const int vk = tid & 31;
  const int vg = tid >> 5;

  for (int t = 0; t < nt; ++t) {
    const int k0 = t * KBLK;
    __syncthreads();

    // stage K hi/lo tiles [32][256], swizzle byte ^= ((row&7)<<4)
#pragma unroll
    for (int p = 0; p < 4; ++p) {
      const int o = (tid << 4) + (p << 12);   // 0..16K-16
      const int krow = o >> 9;
      const int col = o & 511;
      const int so = o ^ ((krow & 7) << 4);
      const char* krbase = Kbytes + (((size_t)b * S_ + k0 + krow) * NKV_ + kvh) * 1024;
      *reinterpret_cast<uint4*>(reinterpret_cast<char*>(Ksh_h) + so) =
          *reinterpret_cast<const uint4*>(krbase + col);
      *reinterpret_cast<uint4*>(reinterpret_cast<char*>(Ksh_l) + so) =
          *reinterpret_cast<const uint4*>(krbase + 512 + col);
    }
    // stage V^T: Vsh[d][k] = V[k0+k][d]
#pragma unroll
    for (int p = 0; p < 4; ++p) {
      const int d0 = vg * 8 + p * 64;
      union { uint4 u4; ushort e[8]; } vv;
      vv.u4 = *reinterpret_cast<const uint4*>(
          Vbytes + (((size_t)b * S_ + k0 + vk) * NKV_ + kvh) * 1024 + d0 * 2);
#pragma unroll
      for (int j = 0; j < 8; ++j) Vsh[(d0 + j) * 36 + vk] = vv.e[j];
    }
    __syncthreads();

    // QK^T, 3-term split precision
    f32x4 s0 = (f32x4){0.f, 0.f, 0.f, 0.f};
    f32x4 s1 = (f32x4){0.f, 0.f, 0.f, 0.f};
#pragma unroll
    for (int c = 0; c < 8; ++c) {
      const int bc = c * 64 + lgrp * 16;
      const int r0 = lrow, r1 = 16 + lrow;
      const int o0 = r0 * 512 + (bc ^ ((r0 & 7) << 4));
      const int o1 = r1 * 512 + (bc ^ ((r1 & 7) << 4));
      bf16x8 kh0 = *reinterpret_cast<const bf16x8*>(reinterpret_cast<const char*>(Ksh_h) + o0);
      bf16x8 kh1 = *reinterpret_cast<const bf16x8*>(reinterpret_cast<const char*>(Ksh_h) + o1);
      bf16x8 kl0 = *reinterpret_cast<const bf16x8*>(reinterpret_cast<const char*>(Ksh_l) + o0);
      bf16x8 kl1 = *reinterpret_cast<const bf16x8*>(reinterpret_cast<const char*>(Ksh_l) + o1);
      s0 = __builtin_amdgcn_mfma_f32_16x16x32_bf16(qf_h[c], kh0, s0, 0, 0, 0);
      s0 = __builtin_amdgcn_mfma_f32_16x16x32_bf16(qf_l[c], kh0, s0, 0, 0, 0);
      s0 = __builtin_amdgcn_mfma_f32_16x16x32_bf16(qf_h[c], kl0, s0, 0, 0, 0);
      s1 = __builtin_amdgcn_mfma_f32_16x16x32_bf16(qf_h[c], kh1, s1, 0, 0, 0);
      s1 = __builtin_amdgcn_mfma_f32_16x16x32_bf16(qf_l[c], kh1, s1, 0, 0, 0);
      s1 = __builtin_amdgcn_mfma_f32_16x16x32_bf16(qf_h[c], kl1, s1, 0, 0, 0);
    }

    // online softmax
    const int qg = q0 + wave * 16 + lgrp * 4;
    float sc_r[4];
#pragma unroll
    for (int reg = 0; reg < 4; ++reg) {
      const int qrow = qg + reg;
      const bool ok0 = (k0 + lrow) <= qrow;
      const bool ok1 = (k0 + 16 + lrow) <= qrow;
      float v0 = ok0 ? s0[reg] : -3e38f;
      float v1 = ok1 ? s1[reg] : -3e38f;
      float mx = fmaxf(v0, v1);
      mx = fmaxf(mx, __shfl_xor(mx, 1));
      mx = fmaxf(mx, __shfl_xor(mx, 2));
      mx = fmaxf(mx, __shfl_xor(mx, 4));
      mx = fmaxf(mx, __shfl_xor(mx, 8));
      const float mnew = fmaxf(m_r[reg], mx);
      const float sc = expf(m_r[reg] - mnew);
      const float p0 = ok0 ? expf(s0[reg] - mnew) : 0.f;
      const float p1 = ok1 ? expf(s1[reg] - mnew) : 0.f;
      float rs = p0 + p1;
      rs += __shfl_xor(rs, 1);
      rs += __shfl_xor(rs, 2);
      rs += __shfl_xor(rs, 4);
      rs += __shfl_xor(rs, 8);
      l_r[reg] = l_r[reg] * sc + rs;
      m_r[reg] = mnew;
      sc_r[reg] = sc;
      Psh[wave][lgrp * 4 + reg][lrow] = f2bf(p0);
      Psh[wave][lgrp * 4 + reg][16 + lrow] = f2bf(p1);
    }
    const f32x4 scv = (f32x4){sc_r[0], sc_r[1], sc_r[2], sc_r[3]};
#pragma unroll
    for (int ch = 0; ch < 16; ++ch) Oacc[ch] *= scv;

    __syncthreads();

    // PV
    bf16x8 pa = *reinterpret_cast<const bf16x8*>(&Psh[wave][lrow][lgrp * 8]);
#pragma unroll
    for (int ch = 0; ch < 16; ++ch) {
      const ushort* vp = &Vsh[(ch * 16 + lrow) * 36 + lgrp * 8];
      union { uint u[4]; bf16x8 v; } tmp;
      const uint2 lo = *reinterpret_cast<const uint2*>(vp);
      const uint2 hi = *reinterpret_cast<const uint2*>(vp + 4);
      tmp.u[0] = lo.x; tmp.u[1] = lo.y; tmp.u[2] = hi.x; tmp.u[3] = hi.y;
      Oacc[ch] = __builtin_amdgcn_mfma_f32_16x16x32_bf16(pa, tmp.v, Oacc[ch], 0, 0, 0);
    }
  }

  // write bf16 output (B,S,NH*HD)
  ushort* obase = O + ((size_t)b * S_ + q0 + wave * 16) * (NH_ * HD_) + (size_t)h * HD_;
#pragma unroll
  for (int reg = 0; reg < 4; ++reg) {
    const float inv = 1.0f / l_r[reg];
    ushort* orow = obase + (size_t)(lgrp * 4 + reg) * (NH_ * HD_);
#pragma unroll
    for (int ch = 0; ch < 16; ++ch)
      orow[ch * 16 + lrow] = f2bf(Oacc[ch][reg] * inv);
  }
}

// ---------------- launch ----------------
extern "C" void kernel_launch(void* const* d_in, const int* in_sizes, int n_in,
                              void* d_out, int out_size, void* d_ws, size_t ws_size,
                              hipStream_t stream) {
  const float* hidden   = (const float*)d_in[0];
  const float* cos_t    = (const float*)d_in[1];
  const float* sin_t    = (const float*)d_in[2];
  const float* q_w      = (const float*)d_in[4];
  const float* k_w      = (const float*)d_in[5];
  const float* v_w      = (const float*)d_in[6];
  const float* o_w      = (const float*)d_in[7];
  const float* q_norm_w = (const float*)d_in[8];
  const float* k_norm_w = (const float*)d_in[9];
  float* out = (float*)d_out;

  // workspace plan (92.3 MB total; round-3 proved >= 96.4 MB available):
  char* ws = (char*)d_ws;
  ushort* hid_hi = (ushort*)(ws);                       // 16.78 MB
  ushort* hid_lo = (ushort*)(ws + 16777216);            // 16.78 MB, later v_proj
  ushort* wslot  = (ushort*)(ws + 33554432);            // 16.78 MB, reused per weight
  float*  q_slot = (float*)(ws + 50331648);             // 33.55 MB
  float*  k_slot = (float*)(ws + 83886080);             // 8.39 MB
  float*  v_slot = (float*)hid_lo;                      // overlay (hid_lo dead after k-gemm)
  ushort* attn_bf = hid_hi;                             // overlay (hid_hi dead after v-gemm)

  const int M = B_ * S_;  // 4096

  // hidden -> hi/lo
  conv_split<<<2048, 256, 0, stream>>>(hidden, hid_hi, hid_lo, (B_ * S_ * HID_) / 4);

  // ---- Q projection (split) ----
  ushort* qw_hi = wslot;
  ushort* qw_lo = wslot + (size_t)NH_ * HD_ * HID_;
  conv_split<<<2048, 256, 0, stream>>>(q_w, qw_hi, qw_lo, (NH_ * HD_ * HID_) / 4);
  gemm_mfma<1><<<dim3((NH_ * HD_) / 128, M / 128), 256, 0, stream>>>(
      hid_hi, hid_lo, qw_hi, qw_lo, q_slot, M, NH_ * HD_, HID_);
  ln_rope_ip<<<M * NH_, 256, 0, stream>>>(q_slot, q_norm_w, cos_t, sin_t, NH_, 1, 1);

  // ---- K projection (split) ----
  ushort* kw_hi = wslot;
  ushort* kw_lo = wslot + (size_t)NKV_ * HD_ * HID_;
  conv_split<<<1024, 256, 0, stream>>>(k_w, kw_hi, kw_lo, (NKV_ * HD_ * HID_) / 4);
  gemm_mfma<1><<<dim3((NKV_ * HD_) / 128, M / 128), 256, 0, stream>>>(
      hid_hi, hid_lo, kw_hi, kw_lo, k_slot, M, NKV_ * HD_, HID_);
  ln_rope_ip<<<M * NKV_, 256, 0, stream>>>(k_slot, k_norm_w, cos_t, sin_t, NKV_, 1, 1);

  // ---- V projection (plain; output overlays hid_lo which is now dead) ----
  ushort* vw_hi = wslot;
  conv_split<<<1024, 256, 0, stream>>>(v_w, vw_hi, nullptr, (NKV_ * HD_ * HID_) / 4);
  gemm_mfma<0><<<dim3((NKV_ * HD_) / 128, M / 128), 256, 0, stream>>>(
      hid_hi, nullptr, vw_hi, nullptr, v_slot, M, NKV_ * HD_, HID_);
  ln_rope_ip<<<M * NKV_, 256, 0, stream>>>(v_slot, nullptr, cos_t, sin_t, NKV_, 0, 0);

  // ---- attention (writes bf16 into hid_hi slot, now dead) ----
  attn_mfma<<<dim3(S_ / QBLK, NH_, B_), 256, 0, stream>>>(
      (const ushort*)q_slot, (const ushort*)k_slot, (const ushort*)v_slot, attn_bf);

  // ---- O projection (plain) ----
  ushort* ow_hi = wslot;
  conv_split<<<2048, 256, 0, stream>>>(o_w, ow_hi, nullptr, (HID_ * NH_ * HD_) / 4);
  gemm_mfma<0><<<dim3(HID_ / 128, M / 128), 256, 0, stream>>>(
      attn_bf, nullptr, ow_hi, nullptr, out, M, HID_, NH_ * HD_);
}

// Round 7
// 863.860 us; speedup vs baseline: 9.7896x; 1.5729x over previous
//
#include <hip/hip_runtime.h>
#include <hip/hip_bf16.h>
#include <cstddef>
#include <cstdint>

#define B_    2
#define S_    2048
#define HID_  2048
#define NH_   8
#define NKV_  2
#define HD_   256
#define NREP_ (NH_ / NKV_)
#define EPS_  1e-6f

#define QBLK 64
#define KBLK 32

typedef short bf16x8 __attribute__((ext_vector_type(8)));
typedef float f32x4 __attribute__((ext_vector_type(4)));

static __device__ __forceinline__ ushort f2bf(float x) {
  uint u = __float_as_uint(x);
  return (ushort)((u + 0x7FFFu + ((u >> 16) & 1u)) >> 16);
}
static __device__ __forceinline__ float bf2f(ushort h) {
  return __uint_as_float(((uint)h) << 16);
}

// async global->LDS, 16B per lane; LDS dest wave-uniform (HW adds lane*16); global src per-lane
static __device__ __forceinline__ void gload16(const void* g, void* l) {
  __builtin_amdgcn_global_load_lds(
      (const __attribute__((address_space(1))) uint*)g,
      (__attribute__((address_space(3))) uint*)l, 16, 0, 0);
}

// ---------------- fp32 -> bf16 hi (+ optional lo residual) ----------------
__global__ __launch_bounds__(256) void conv_split(const float* __restrict__ in,
                                                  ushort* __restrict__ hi,
                                                  ushort* __restrict__ lo,
                                                  int n4) {
  int i = blockIdx.x * 256 + threadIdx.x;
  const int stride = gridDim.x * 256;
  for (; i < n4; i += stride) {
    const float4 x = reinterpret_cast<const float4*>(in)[i];
    ushort4 h;
    h.x = f2bf(x.x); h.y = f2bf(x.y); h.z = f2bf(x.z); h.w = f2bf(x.w);
    reinterpret_cast<ushort4*>(hi)[i] = h;
    if (lo) {
      ushort4 l;
      l.x = f2bf(x.x - bf2f(h.x)); l.y = f2bf(x.y - bf2f(h.y));
      l.z = f2bf(x.z - bf2f(h.z)); l.w = f2bf(x.w - bf2f(h.w));
      reinterpret_cast<ushort4*>(lo)[i] = l;
    }
  }
}

// ---------------- bf16 MFMA GEMM: C[M,N] = A[M,K] @ W[N,K]^T ----------------
template <int SPLIT>
__global__ __launch_bounds__(256) void gemm_mfma(const ushort* __restrict__ Ah,
                                                 const ushort* __restrict__ Al,
                                                 const ushort* __restrict__ Wh,
                                                 const ushort* __restrict__ Wl,
                                                 float* __restrict__ C,
                                                 int M, int N, int K) {
  __shared__ __align__(16) ushort AshH[4096];
  __shared__ __align__(16) ushort BshH[4096];
  __shared__ __align__(16) ushort AshL[SPLIT ? 4096 : 8];
  __shared__ __align__(16) ushort BshL[SPLIT ? 4096 : 8];

  const int bm = blockIdx.y * 128;
  const int bn = blockIdx.x * 128;
  const int tid = threadIdx.x;
  const int wave = tid >> 6;
  const int lane = tid & 63;
  const int wr = wave >> 1;
  const int wc = wave & 1;
  const int lrow = lane & 15;
  const int lgrp = lane >> 4;

  f32x4 acc[4][4];
#pragma unroll
  for (int m = 0; m < 4; ++m)
#pragma unroll
    for (int n = 0; n < 4; ++n) acc[m][n] = (f32x4){0.f, 0.f, 0.f, 0.f};

  for (int k0 = 0; k0 < K; k0 += 32) {
    __syncthreads();
#pragma unroll
    for (int s = 0; s < 2; ++s) {
      const int seg = wave * 2 + s;
      const int kc = seg >> 1;
      const int rb = (seg & 1) * 64;
      const size_t gofs = (size_t)(bm + rb + lane) * K + k0 + kc * 8;
      const size_t gofsB = (size_t)(bn + rb + lane) * K + k0 + kc * 8;
      const int lofs = (kc * 128 + rb) * 16;
      gload16(Ah + gofs, (char*)AshH + lofs);
      gload16(Wh + gofsB, (char*)BshH + lofs);
      if constexpr (SPLIT) {
        gload16(Al + gofs, (char*)AshL + lofs);
        gload16(Wl + gofsB, (char*)BshL + lofs);
      }
    }
    __syncthreads();

    bf16x8 af[4], bfr[4], afl[4], bfl[4];
#pragma unroll
    for (int m = 0; m < 4; ++m) {
      const int r = wr * 64 + m * 16 + lrow;
      af[m] = *reinterpret_cast<const bf16x8*>((const char*)AshH + (lgrp * 128 + r) * 16);
      if constexpr (SPLIT)
        afl[m] = *reinterpret_cast<const bf16x8*>((const char*)AshL + (lgrp * 128 + r) * 16);
    }
#pragma unroll
    for (int n = 0; n < 4; ++n) {
      const int c = wc * 64 + n * 16 + lrow;
      bfr[n] = *reinterpret_cast<const bf16x8*>((const char*)BshH + (lgrp * 128 + c) * 16);
      if constexpr (SPLIT)
        bfl[n] = *reinterpret_cast<const bf16x8*>((const char*)BshL + (lgrp * 128 + c) * 16);
    }
#pragma unroll
    for (int m = 0; m < 4; ++m)
#pragma unroll
      for (int n = 0; n < 4; ++n) {
        acc[m][n] = __builtin_amdgcn_mfma_f32_16x16x32_bf16(af[m], bfr[n], acc[m][n], 0, 0, 0);
        if constexpr (SPLIT) {
          acc[m][n] = __builtin_amdgcn_mfma_f32_16x16x32_bf16(afl[m], bfr[n], acc[m][n], 0, 0, 0);
          acc[m][n] = __builtin_amdgcn_mfma_f32_16x16x32_bf16(af[m], bfl[n], acc[m][n], 0, 0, 0);
        }
      }
  }

#pragma unroll
  for (int m = 0; m < 4; ++m) {
    const int row0 = bm + wr * 64 + m * 16 + lgrp * 4;
#pragma unroll
    for (int n = 0; n < 4; ++n) {
      const int col = bn + wc * 64 + n * 16 + lrow;
#pragma unroll
      for (int reg = 0; reg < 4; ++reg)
        C[(size_t)(row0 + reg) * N + col] = acc[m][n][reg];
    }
  }
}

// ---------------- in-place LayerNorm (+RoPE), fp32 row -> [hi 256 | lo 256] ushorts ----------------
__global__ __launch_bounds__(256) void ln_rope_ip(float* __restrict__ io,
                                                  const float* __restrict__ w,
                                                  const float* __restrict__ cos_t,
                                                  const float* __restrict__ sin_t,
                                                  int nheads, int do_rope, int do_split) {
  const int blk = blockIdx.x;
  const int s = (blk / nheads) % S_;
  const int b = blk / (nheads * S_);
  const int d = threadIdx.x;
  __shared__ float red[256];
  __shared__ float ybuf[256];

  const float x = io[(size_t)blk * HD_ + d];

  red[d] = x;
  __syncthreads();
#pragma unroll
  for (int off = 128; off > 0; off >>= 1) {
    if (d < off) red[d] += red[d + off];
    __syncthreads();
  }
  const float mean = red[0] * (1.0f / HD_);
  __syncthreads();

  const float xc = x - mean;
  red[d] = xc * xc;
  __syncthreads();
#pragma unroll
  for (int off = 128; off > 0; off >>= 1) {
    if (d < off) red[d] += red[d + off];
    __syncthreads();
  }
  const float var = red[0] * (1.0f / HD_);

  const float wd = w ? w[d] : 1.0f;
  const float y = xc * rsqrtf(var + EPS_) * wd;

  float o;
  if (do_rope) {
    ybuf[d] = y;
    __syncthreads();
    const float rot = (d < HD_ / 2) ? -ybuf[d + HD_ / 2] : ybuf[d - HD_ / 2];
    const size_t cidx = ((size_t)b * S_ + s) * HD_ + d;
    o = y * cos_t[cidx] + rot * sin_t[cidx];
  } else {
    o = y;
  }
  ushort* us = reinterpret_cast<ushort*>(io);
  const ushort hi = f2bf(o);
  us[(size_t)blk * 512 + d] = hi;
  if (do_split) us[(size_t)blk * 512 + 256 + d] = f2bf(o - bf2f(hi));
}

// ---------------- MFMA flash attention: balanced pairs + double-buffered pipeline ----------------
// block = q-tile pair {qi, 31-qi}, one (b,h). 4 waves x 16 rows. KV tiles of 32, dbuf.
// Q rows packed [hi|lo] at ((b*S+s)*NH+h)*512; K same w/ NKV; V hi-only. O bf16 (B,S,NH*HD).
__global__ __launch_bounds__(256) void attn_mfma(const ushort* __restrict__ Q,
                                                 const ushort* __restrict__ K,
                                                 const ushort* __restrict__ V,
                                                 ushort* __restrict__ O) {
  const int h = blockIdx.y;
  const int b = blockIdx.z;
  const int kvh = h / NREP_;
  const int tid = threadIdx.x;
  const int wave = tid >> 6;
  const int lane = tid & 63;
  const int lrow = lane & 15;
  const int lgrp = lane >> 4;

  __shared__ ushort KshH[2][KBLK * 256];  // 2 x 16 KB, swizzled layout (XOR on read)
  __shared__ ushort KshL[2][KBLK * 256];  // 2 x 16 KB
  __shared__ ushort Vsh[2][256 * 36];     // 2 x 18 KB, V^T padded stride 36
  __shared__ ushort Psh[4][16][40];       // 5 KB, wave-private

  const char* Kbytes = reinterpret_cast<const char*>(K);
  const char* Vbytes = reinterpret_cast<const char*>(V);
  const int vk = tid & 31;
  const int vg = tid >> 5;

  // stage K tile (hi+lo) via global_load_lds: linear LDS dest, source pre-swizzled so that
  // reading LDS at (row*512 + (col ^ ((row&7)<<4))) yields K[row][col].
  auto issueK = [&](int bufi, int k0) {
#pragma unroll
    for (int p = 0; p < 4; ++p) {
      const int sg = p * 4 + wave;                 // 0..15, wave-uniform
      const int o = (sg << 10) + lane * 16;        // dest byte in 16KB tile
      const int row = o >> 9;
      const int colg = (o & 511) ^ ((row & 7) << 4);
      const char* kr = Kbytes + ((((size_t)b * S_ + k0 + row) * NKV_ + kvh) << 10);
      gload16(kr + colg, (char*)KshH[bufi] + (sg << 10));
      gload16(kr + 512 + colg, (char*)KshL[bufi] + (sg << 10));
    }
  };
  auto issueV = [&](uint4* vpf, int k0) {
#pragma unroll
    for (int p = 0; p < 4; ++p)
      vpf[p] = *reinterpret_cast<const uint4*>(
          Vbytes + ((((size_t)b * S_ + k0 + vk) * NKV_ + kvh) << 10) + (vg * 8 + p * 64) * 2);
  };
  auto writeV = [&](int bufi, const uint4* vpf) {
#pragma unroll
    for (int p = 0; p < 4; ++p) {
      const int d0 = vg * 8 + p * 64;
      union { uint4 u4; ushort e[8]; } vv;
      vv.u4 = vpf[p];
#pragma unroll
      for (int j = 0; j < 8; ++j) Vsh[bufi][(d0 + j) * 36 + vk] = vv.e[j];
    }
  };

  for (int half = 0; half < 2; ++half) {
    const int qi = half ? (31 - (int)blockIdx.x) : (int)blockIdx.x;
    const int q0 = qi * QBLK;
    const int nt = 2 * qi + 2;  // KV tiles covering keys < q0+64

    // Q fragments (hi+lo), 16 rows per wave
    const ushort* Qrow = Q + (((size_t)b * S_ + q0 + wave * 16 + lrow) * NH_ + h) * 512;
    bf16x8 qf_h[8], qf_l[8];
#pragma unroll
    for (int c = 0; c < 8; ++c) {
      qf_h[c] = *reinterpret_cast<const bf16x8*>(Qrow + c * 32 + lgrp * 8);
      qf_l[c] = *reinterpret_cast<const bf16x8*>(Qrow + 256 + c * 32 + lgrp * 8);
    }

    f32x4 Oacc[16];
#pragma unroll
    for (int i = 0; i < 16; ++i) Oacc[i] = (f32x4){0.f, 0.f, 0.f, 0.f};
    float m_r[4] = {-3e38f, -3e38f, -3e38f, -3e38f};
    float l_r[4] = {0.f, 0.f, 0.f, 0.f};

    // prologue: stage tile 0 into buf 0
    uint4 vpf[4];
    issueK(0, 0);
    issueV(vpf, 0);
    writeV(0, vpf);
    __syncthreads();  // compiler drains vmcnt before barrier
    int cur = 0;

    for (int t = 0; t < nt; ++t) {
      const int k0 = t * KBLK;
      const bool pf = (t + 1 < nt);
      if (pf) {  // prefetch next tile while computing this one
        issueK(cur ^ 1, k0 + KBLK);
        issueV(vpf, k0 + KBLK);
      }

      // ---- QK^T: 3-term split precision, 2 independent chains per half-tile ----
      f32x4 s0a = (f32x4){0.f, 0.f, 0.f, 0.f}, s0b = s0a, s1a = s0a, s1b = s0a;
#pragma unroll
      for (int c = 0; c < 8; ++c) {
        const int bc = c * 64 + lgrp * 16;
        const int r0 = lrow, r1 = 16 + lrow;
        const int o0 = r0 * 512 + (bc ^ ((r0 & 7) << 4));
        const int o1 = r1 * 512 + (bc ^ ((r1 & 7) << 4));
        bf16x8 kh0 = *reinterpret_cast<const bf16x8*>((const char*)KshH[cur] + o0);
        bf16x8 kh1 = *reinterpret_cast<const bf16x8*>((const char*)KshH[cur] + o1);
        bf16x8 kl0 = *reinterpret_cast<const bf16x8*>((const char*)KshL[cur] + o0);
        bf16x8 kl1 = *reinterpret_cast<const bf16x8*>((const char*)KshL[cur] + o1);
        s0a = __builtin_amdgcn_mfma_f32_16x16x32_bf16(qf_h[c], kh0, s0a, 0, 0, 0);
        s0b = __builtin_amdgcn_mfma_f32_16x16x32_bf16(qf_l[c], kh0, s0b, 0, 0, 0);
        s0b = __builtin_amdgcn_mfma_f32_16x16x32_bf16(qf_h[c], kl0, s0b, 0, 0, 0);
        s1a = __builtin_amdgcn_mfma_f32_16x16x32_bf16(qf_h[c], kh1, s1a, 0, 0, 0);
        s1b = __builtin_amdgcn_mfma_f32_16x16x32_bf16(qf_l[c], kh1, s1b, 0, 0, 0);
        s1b = __builtin_amdgcn_mfma_f32_16x16x32_bf16(qf_h[c], kl1, s1b, 0, 0, 0);
      }
      const f32x4 s0 = s0a + s0b;
      const f32x4 s1 = s1a + s1b;

      // ---- online softmax (row = lgrp*4+reg, key-col = lrow) ----
      const int qg = q0 + wave * 16 + lgrp * 4;
      float sc_r[4];
#pragma unroll
      for (int reg = 0; reg < 4; ++reg) {
        const int qrow = qg + reg;
        const bool ok0 = (k0 + lrow) <= qrow;
        const bool ok1 = (k0 + 16 + lrow) <= qrow;
        float v0 = ok0 ? s0[reg] : -3e38f;
        float v1 = ok1 ? s1[reg] : -3e38f;
        float mx = fmaxf(v0, v1);
        mx = fmaxf(mx, __shfl_xor(mx, 1));
        mx = fmaxf(mx, __shfl_xor(mx, 2));
        mx = fmaxf(mx, __shfl_xor(mx, 4));
        mx = fmaxf(mx, __shfl_xor(mx, 8));
        const float mnew = fmaxf(m_r[reg], mx);
        const float sc = expf(m_r[reg] - mnew);
        const float p0 = ok0 ? expf(s0[reg] - mnew) : 0.f;
        const float p1 = ok1 ? expf(s1[reg] - mnew) : 0.f;
        float rs = p0 + p1;
        rs += __shfl_xor(rs, 1);
        rs += __shfl_xor(rs, 2);
        rs += __shfl_xor(rs, 4);
        rs += __shfl_xor(rs, 8);
        l_r[reg] = l_r[reg] * sc + rs;
        m_r[reg] = mnew;
        sc_r[reg] = sc;
        Psh[wave][lgrp * 4 + reg][lrow] = f2bf(p0);
        Psh[wave][lgrp * 4 + reg][16 + lrow] = f2bf(p1);
      }
      const f32x4 scv = (f32x4){sc_r[0], sc_r[1], sc_r[2], sc_r[3]};
#pragma unroll
      for (int ch = 0; ch < 16; ++ch) Oacc[ch] *= scv;

      // ---- PV (Psh is wave-private: wave-internal ds ordering, no barrier needed) ----
      bf16x8 pa = *reinterpret_cast<const bf16x8*>(&Psh[wave][lrow][lgrp * 8]);
#pragma unroll
      for (int ch = 0; ch < 16; ++ch) {
        const ushort* vp = &Vsh[cur][(ch * 16 + lrow) * 36 + lgrp * 8];
        union { uint u[4]; bf16x8 v; } tmp;
        const uint2 lo = *reinterpret_cast<const uint2*>(vp);
        const uint2 hi = *reinterpret_cast<const uint2*>(vp + 4);
        tmp.u[0] = lo.x; tmp.u[1] = lo.y; tmp.u[2] = hi.x; tmp.u[3] = hi.y;
        Oacc[ch] = __builtin_amdgcn_mfma_f32_16x16x32_bf16(pa, tmp.v, Oacc[ch], 0, 0, 0);
      }

      if (pf) writeV(cur ^ 1, vpf);  // compiler waits vmcnt for vpf before ds_write
      __syncthreads();               // staging of t+1 visible; buffers safe to swap
      cur ^= 1;
    }

    // ---- write bf16 output for this half ----
    ushort* obase = O + ((size_t)b * S_ + q0 + wave * 16) * (NH_ * HD_) + (size_t)h * HD_;
#pragma unroll
    for (int reg = 0; reg < 4; ++reg) {
      const float inv = 1.0f / l_r[reg];
      ushort* orow = obase + (size_t)(lgrp * 4 + reg) * (NH_ * HD_);
#pragma unroll
      for (int ch = 0; ch < 16; ++ch)
        orow[ch * 16 + lrow] = f2bf(Oacc[ch][reg] * inv);
    }
  }
}

// ---------------- launch ----------------
extern "C" void kernel_launch(void* const* d_in, const int* in_sizes, int n_in,
                              void* d_out, int out_size, void* d_ws, size_t ws_size,
                              hipStream_t stream) {
  const float* hidden   = (const float*)d_in[0];
  const float* cos_t    = (const float*)d_in[1];
  const float* sin_t    = (const float*)d_in[2];
  const float* q_w      = (const float*)d_in[4];
  const float* k_w      = (const float*)d_in[5];
  const float* v_w      = (const float*)d_in[6];
  const float* o_w      = (const float*)d_in[7];
  const float* q_norm_w = (const float*)d_in[8];
  const float* k_norm_w = (const float*)d_in[9];
  float* out = (float*)d_out;

  char* ws = (char*)d_ws;
  ushort* hid_hi = (ushort*)(ws);                       // 16.78 MB
  ushort* hid_lo = (ushort*)(ws + 16777216);            // 16.78 MB, later v_proj
  ushort* wslot  = (ushort*)(ws + 33554432);            // 16.78 MB, reused per weight
  float*  q_slot = (float*)(ws + 50331648);             // 33.55 MB
  float*  k_slot = (float*)(ws + 83886080);             // 8.39 MB
  float*  v_slot = (float*)hid_lo;                      // overlay (hid_lo dead after k-gemm)
  ushort* attn_bf = hid_hi;                             // overlay (hid_hi dead after v-gemm)

  const int M = B_ * S_;  // 4096

  conv_split<<<2048, 256, 0, stream>>>(hidden, hid_hi, hid_lo, (B_ * S_ * HID_) / 4);

  // ---- Q projection (split) ----
  ushort* qw_hi = wslot;
  ushort* qw_lo = wslot + (size_t)NH_ * HD_ * HID_;
  conv_split<<<2048, 256, 0, stream>>>(q_w, qw_hi, qw_lo, (NH_ * HD_ * HID_) / 4);
  gemm_mfma<1><<<dim3((NH_ * HD_) / 128, M / 128), 256, 0, stream>>>(
      hid_hi, hid_lo, qw_hi, qw_lo, q_slot, M, NH_ * HD_, HID_);
  ln_rope_ip<<<M * NH_, 256, 0, stream>>>(q_slot, q_norm_w, cos_t, sin_t, NH_, 1, 1);

  // ---- K projection (split) ----
  ushort* kw_hi = wslot;
  ushort* kw_lo = wslot + (size_t)NKV_ * HD_ * HID_;
  conv_split<<<1024, 256, 0, stream>>>(k_w, kw_hi, kw_lo, (NKV_ * HD_ * HID_) / 4);
  gemm_mfma<1><<<dim3((NKV_ * HD_) / 128, M / 128), 256, 0, stream>>>(
      hid_hi, hid_lo, kw_hi, kw_lo, k_slot, M, NKV_ * HD_, HID_);
  ln_rope_ip<<<M * NKV_, 256, 0, stream>>>(k_slot, k_norm_w, cos_t, sin_t, NKV_, 1, 1);

  // ---- V projection (plain) ----
  ushort* vw_hi = wslot;
  conv_split<<<1024, 256, 0, stream>>>(v_w, vw_hi, nullptr, (NKV_ * HD_ * HID_) / 4);
  gemm_mfma<0><<<dim3((NKV_ * HD_) / 128, M / 128), 256, 0, stream>>>(
      hid_hi, nullptr, vw_hi, nullptr, v_slot, M, NKV_ * HD_, HID_);
  ln_rope_ip<<<M * NKV_, 256, 0, stream>>>(v_slot, nullptr, cos_t, sin_t, NKV_, 0, 0);

  // ---- attention: 256 balanced blocks (pair qi with 31-qi), 1 block/CU ----
  attn_mfma<<<dim3(16, NH_, B_), 256, 0, stream>>>(
      (const ushort*)q_slot, (const ushort*)k_slot, (const ushort*)v_slot, attn_bf);

  // ---- O projection (plain) ----
  ushort* ow_hi = wslot;
  conv_split<<<2048, 256, 0, stream>>>(o_w, ow_hi, nullptr, (HID_ * NH_ * HD_) / 4);
  gemm_mfma<0><<<dim3(HID_ / 128, M / 128), 256, 0, stream>>>(
      attn_bf, nullptr, ow_hi, nullptr, out, M, HID_, NH_ * HD_);
}

// Round 12
// 799.325 us; speedup vs baseline: 10.5800x; 1.0807x over previous
//
#include <hip/hip_runtime.h>
#include <hip/hip_bf16.h>
#include <cstddef>
#include <cstdint>

#define B_    2
#define S_    2048
#define HID_  2048
#define NH_   8
#define NKV_  2
#define HD_   256
#define NREP_ (NH_ / NKV_)
#define EPS_  1e-6f

#define QBLK 64
#define KBLK 32

typedef short bf16x8 __attribute__((ext_vector_type(8)));
typedef float f32x4 __attribute__((ext_vector_type(4)));

static __device__ __forceinline__ ushort f2bf(float x) {
  uint u = __float_as_uint(x);
  return (ushort)((u + 0x7FFFu + ((u >> 16) & 1u)) >> 16);
}
static __device__ __forceinline__ float bf2f(ushort h) {
  return __uint_as_float(((uint)h) << 16);
}

// async global->LDS, 16B per lane; LDS dest wave-uniform (HW adds lane*16); global src per-lane
static __device__ __forceinline__ void gload16(const void* g, void* l) {
  __builtin_amdgcn_global_load_lds(
      (const __attribute__((address_space(1))) uint*)g,
      (__attribute__((address_space(3))) uint*)l, 16, 0, 0);
}

// ---------------- fp32 -> bf16 hi (+ optional lo residual) ----------------
__global__ __launch_bounds__(256) void conv_split(const float* __restrict__ in,
                                                  ushort* __restrict__ hi,
                                                  ushort* __restrict__ lo,
                                                  int n4) {
  int i = blockIdx.x * 256 + threadIdx.x;
  const int stride = gridDim.x * 256;
  for (; i < n4; i += stride) {
    const float4 x = reinterpret_cast<const float4*>(in)[i];
    ushort4 h;
    h.x = f2bf(x.x); h.y = f2bf(x.y); h.z = f2bf(x.z); h.w = f2bf(x.w);
    reinterpret_cast<ushort4*>(hi)[i] = h;
    if (lo) {
      ushort4 l;
      l.x = f2bf(x.x - bf2f(h.x)); l.y = f2bf(x.y - bf2f(h.y));
      l.z = f2bf(x.z - bf2f(h.z)); l.w = f2bf(x.w - bf2f(h.w));
      reinterpret_cast<ushort4*>(lo)[i] = l;
    }
  }
}

// ---------------- bf16 MFMA GEMM: C[M,N] = A[M,K] @ W[N,K]^T ----------------
template <int SPLIT>
__global__ __launch_bounds__(256) void gemm_mfma(const ushort* __restrict__ Ah,
                                                 const ushort* __restrict__ Al,
                                                 const ushort* __restrict__ Wh,
                                                 const ushort* __restrict__ Wl,
                                                 float* __restrict__ C,
                                                 int M, int N, int K) {
  __shared__ __align__(16) ushort AshH[4096];
  __shared__ __align__(16) ushort BshH[4096];
  __shared__ __align__(16) ushort AshL[SPLIT ? 4096 : 8];
  __shared__ __align__(16) ushort BshL[SPLIT ? 4096 : 8];

  const int bm = blockIdx.y * 128;
  const int bn = blockIdx.x * 128;
  const int tid = threadIdx.x;
  const int wave = tid >> 6;
  const int lane = tid & 63;
  const int wr = wave >> 1;
  const int wc = wave & 1;
  const int lrow = lane & 15;
  const int lgrp = lane >> 4;

  f32x4 acc[4][4];
#pragma unroll
  for (int m = 0; m < 4; ++m)
#pragma unroll
    for (int n = 0; n < 4; ++n) acc[m][n] = (f32x4){0.f, 0.f, 0.f, 0.f};

  for (int k0 = 0; k0 < K; k0 += 32) {
    __syncthreads();
#pragma unroll
    for (int s = 0; s < 2; ++s) {
      const int seg = wave * 2 + s;
      const int kc = seg >> 1;
      const int rb = (seg & 1) * 64;
      const size_t gofs = (size_t)(bm + rb + lane) * K + k0 + kc * 8;
      const size_t gofsB = (size_t)(bn + rb + lane) * K + k0 + kc * 8;
      const int lofs = (kc * 128 + rb) * 16;
      gload16(Ah + gofs, (char*)AshH + lofs);
      gload16(Wh + gofsB, (char*)BshH + lofs);
      if constexpr (SPLIT) {
        gload16(Al + gofs, (char*)AshL + lofs);
        gload16(Wl + gofsB, (char*)BshL + lofs);
      }
    }
    __syncthreads();

    bf16x8 af[4], bfr[4], afl[4], bfl[4];
#pragma unroll
    for (int m = 0; m < 4; ++m) {
      const int r = wr * 64 + m * 16 + lrow;
      af[m] = *reinterpret_cast<const bf16x8*>((const char*)AshH + (lgrp * 128 + r) * 16);
      if constexpr (SPLIT)
        afl[m] = *reinterpret_cast<const bf16x8*>((const char*)AshL + (lgrp * 128 + r) * 16);
    }
#pragma unroll
    for (int n = 0; n < 4; ++n) {
      const int c = wc * 64 + n * 16 + lrow;
      bfr[n] = *reinterpret_cast<const bf16x8*>((const char*)BshH + (lgrp * 128 + c) * 16);
      if constexpr (SPLIT)
        bfl[n] = *reinterpret_cast<const bf16x8*>((const char*)BshL + (lgrp * 128 + c) * 16);
    }
#pragma unroll
    for (int m = 0; m < 4; ++m)
#pragma unroll
      for (int n = 0; n < 4; ++n) {
        acc[m][n] = __builtin_amdgcn_mfma_f32_16x16x32_bf16(af[m], bfr[n], acc[m][n], 0, 0, 0);
        if constexpr (SPLIT) {
          acc[m][n] = __builtin_amdgcn_mfma_f32_16x16x32_bf16(afl[m], bfr[n], acc[m][n], 0, 0, 0);
          acc[m][n] = __builtin_amdgcn_mfma_f32_16x16x32_bf16(af[m], bfl[n], acc[m][n], 0, 0, 0);
        }
      }
  }

#pragma unroll
  for (int m = 0; m < 4; ++m) {
    const int row0 = bm + wr * 64 + m * 16 + lgrp * 4;
#pragma unroll
    for (int n = 0; n < 4; ++n) {
      const int col = bn + wc * 64 + n * 16 + lrow;
#pragma unroll
      for (int reg = 0; reg < 4; ++reg)
        C[(size_t)(row0 + reg) * N + col] = acc[m][n][reg];
    }
  }
}

// ---------------- in-place LayerNorm (+RoPE), fp32 row -> [hi 256 | lo 256] ushorts ----------------
__global__ __launch_bounds__(256) void ln_rope_ip(float* __restrict__ io,
                                                  const float* __restrict__ w,
                                                  const float* __restrict__ cos_t,
                                                  const float* __restrict__ sin_t,
                                                  int nheads, int do_rope, int do_split) {
  const int blk = blockIdx.x;
  const int s = (blk / nheads) % S_;
  const int b = blk / (nheads * S_);
  const int d = threadIdx.x;
  __shared__ float red[256];
  __shared__ float ybuf[256];

  const float x = io[(size_t)blk * HD_ + d];

  red[d] = x;
  __syncthreads();
#pragma unroll
  for (int off = 128; off > 0; off >>= 1) {
    if (d < off) red[d] += red[d + off];
    __syncthreads();
  }
  const float mean = red[0] * (1.0f / HD_);
  __syncthreads();

  const float xc = x - mean;
  red[d] = xc * xc;
  __syncthreads();
#pragma unroll
  for (int off = 128; off > 0; off >>= 1) {
    if (d < off) red[d] += red[d + off];
    __syncthreads();
  }
  const float var = red[0] * (1.0f / HD_);

  const float wd = w ? w[d] : 1.0f;
  const float y = xc * rsqrtf(var + EPS_) * wd;

  float o;
  if (do_rope) {
    ybuf[d] = y;
    __syncthreads();
    const float rot = (d < HD_ / 2) ? -ybuf[d + HD_ / 2] : ybuf[d - HD_ / 2];
    const size_t cidx = ((size_t)b * S_ + s) * HD_ + d;
    o = y * cos_t[cidx] + rot * sin_t[cidx];
  } else {
    o = y;
  }
  ushort* us = reinterpret_cast<ushort*>(io);
  const ushort hi = f2bf(o);
  us[(size_t)blk * 512 + d] = hi;
  if (do_split) us[(size_t)blk * 512 + 256 + d] = f2bf(o - bf2f(hi));
}

// ---------------- MFMA flash attention: swapped QK^T (lane-local softmax rows) ----------------
// block = q-tile pair {qi, 31-qi}, one (b,h). 4 waves x 16 rows. KV tiles of 32, dbuf.
// S-swap: mfma(K, Q) -> lane holds 8 scores of q-row (lane&15); k = 4*(lane>>4)+reg (+16).
__global__ __launch_bounds__(256) void attn_mfma(const ushort* __restrict__ Q,
                                                 const ushort* __restrict__ K,
                                                 const ushort* __restrict__ V,
                                                 ushort* __restrict__ O) {
  const int h = blockIdx.y;
  const int b = blockIdx.z;
  const int kvh = h / NREP_;
  const int tid = threadIdx.x;
  const int wave = tid >> 6;
  const int lane = tid & 63;
  const int lrow = lane & 15;
  const int lgrp = lane >> 4;

  __shared__ ushort KshH[2][KBLK * 256];  // 2 x 16 KB, swizzled (XOR on read)
  __shared__ ushort KshL[2][KBLK * 256];  // 2 x 16 KB
  __shared__ ushort Vsh[2][256 * 36];     // 2 x 18 KB, V^T padded stride 36
  __shared__ ushort Psh[4][16][40];       // 5 KB, wave-private

  const char* Kbytes = reinterpret_cast<const char*>(K);
  const char* Vbytes = reinterpret_cast<const char*>(V);
  const int vk = tid & 31;
  const int vg = tid >> 5;

  auto issueK = [&](int bufi, int k0) {
#pragma unroll
    for (int p = 0; p < 4; ++p) {
      const int sg = p * 4 + wave;                 // 0..15, wave-uniform
      const int o = (sg << 10) + lane * 16;        // dest byte in 16KB tile
      const int row = o >> 9;
      const int colg = (o & 511) ^ ((row & 7) << 4);
      const char* kr = Kbytes + ((((size_t)b * S_ + k0 + row) * NKV_ + kvh) << 10);
      gload16(kr + colg, (char*)KshH[bufi] + (sg << 10));
      gload16(kr + 512 + colg, (char*)KshL[bufi] + (sg << 10));
    }
  };
  auto issueV = [&](uint4* vpf, int k0) {
#pragma unroll
    for (int p = 0; p < 4; ++p)
      vpf[p] = *reinterpret_cast<const uint4*>(
          Vbytes + ((((size_t)b * S_ + k0 + vk) * NKV_ + kvh) << 10) + (vg * 8 + p * 64) * 2);
  };
  auto writeV = [&](int bufi, const uint4* vpf) {
#pragma unroll
    for (int p = 0; p < 4; ++p) {
      const int d0 = vg * 8 + p * 64;
      union { uint4 u4; ushort e[8]; } vv;
      vv.u4 = vpf[p];
#pragma unroll
      for (int j = 0; j < 8; ++j) Vsh[bufi][(d0 + j) * 36 + vk] = vv.e[j];
    }
  };

  for (int half = 0; half < 2; ++half) {
    const int qi = half ? (31 - (int)blockIdx.x) : (int)blockIdx.x;
    const int q0 = qi * QBLK;
    const int nt = 2 * qi + 2;

    const ushort* Qrow = Q + (((size_t)b * S_ + q0 + wave * 16 + lrow) * NH_ + h) * 512;
    bf16x8 qf_h[8], qf_l[8];
#pragma unroll
    for (int c = 0; c < 8; ++c) {
      qf_h[c] = *reinterpret_cast<const bf16x8*>(Qrow + c * 32 + lgrp * 8);
      qf_l[c] = *reinterpret_cast<const bf16x8*>(Qrow + 256 + c * 32 + lgrp * 8);
    }

    f32x4 Oacc[16];
#pragma unroll
    for (int i = 0; i < 16; ++i) Oacc[i] = (f32x4){0.f, 0.f, 0.f, 0.f};
    float m_l = -3e38f;  // this lane's q-row (= q0+wave*16+lrow) running max
    float l_l = 0.f;     // running denom

    const int qrow = q0 + wave * 16 + lrow;  // lane's q-row (softmax owner)

    uint4 vpf[4];
    issueK(0, 0);
    issueV(vpf, 0);
    writeV(0, vpf);
    __syncthreads();
    int cur = 0;

    for (int t = 0; t < nt; ++t) {
      const int k0 = t * KBLK;
      const bool pf = (t + 1 < nt);
      if (pf) {
        issueK(cur ^ 1, k0 + KBLK);
        issueV(vpf, k0 + KBLK);
      }

      // ---- QK^T swapped: S = K·Q^T; D[col=q (lane&15), row=k (4*lgrp+reg)] ----
      f32x4 s0a = (f32x4){0.f, 0.f, 0.f, 0.f}, s0b = s0a, s1a = s0a, s1b = s0a;
#pragma unroll
      for (int c = 0; c < 8; ++c) {
        const int bc = c * 64 + lgrp * 16;
        const int r0 = lrow, r1 = 16 + lrow;
        const int o0 = r0 * 512 + (bc ^ ((r0 & 7) << 4));
        const int o1 = r1 * 512 + (bc ^ ((r1 & 7) << 4));
        bf16x8 kh0 = *reinterpret_cast<const bf16x8*>((const char*)KshH[cur] + o0);
        bf16x8 kh1 = *reinterpret_cast<const bf16x8*>((const char*)KshH[cur] + o1);
        bf16x8 kl0 = *reinterpret_cast<const bf16x8*>((const char*)KshL[cur] + o0);
        bf16x8 kl1 = *reinterpret_cast<const bf16x8*>((const char*)KshL[cur] + o1);
        s0a = __builtin_amdgcn_mfma_f32_16x16x32_bf16(kh0, qf_h[c], s0a, 0, 0, 0);
        s0b = __builtin_amdgcn_mfma_f32_16x16x32_bf16(kh0, qf_l[c], s0b, 0, 0, 0);
        s0b = __builtin_amdgcn_mfma_f32_16x16x32_bf16(kl0, qf_h[c], s0b, 0, 0, 0);
        s1a = __builtin_amdgcn_mfma_f32_16x16x32_bf16(kh1, qf_h[c], s1a, 0, 0, 0);
        s1b = __builtin_amdgcn_mfma_f32_16x16x32_bf16(kh1, qf_l[c], s1b, 0, 0, 0);
        s1b = __builtin_amdgcn_mfma_f32_16x16x32_bf16(kl1, qf_h[c], s1b, 0, 0, 0);
      }
      const f32x4 s0 = s0a + s0b;  // k = k0 + 4*lgrp + reg
      const f32x4 s1 = s1a + s1b;  // k = k0 + 16 + 4*lgrp + reg

      // ---- lane-local softmax for q-row `qrow` ----
      bool oklo[4], okhi[4];
      float mx = -3e38f;
#pragma unroll
      for (int reg = 0; reg < 4; ++reg) {
        oklo[reg] = (k0 + 4 * lgrp + reg) <= qrow;
        okhi[reg] = (k0 + 16 + 4 * lgrp + reg) <= qrow;
        const float vlo = oklo[reg] ? s0[reg] : -3e38f;
        const float vhi = okhi[reg] ? s1[reg] : -3e38f;
        mx = fmaxf(mx, fmaxf(vlo, vhi));
      }
      mx = fmaxf(mx, __shfl_xor(mx, 16));
      mx = fmaxf(mx, __shfl_xor(mx, 32));
      const float mnew = fmaxf(m_l, mx);
      const float sc = __expf(m_l - mnew);
      float rs = 0.f;
#pragma unroll
      for (int reg = 0; reg < 4; ++reg) {
        const float plo = oklo[reg] ? __expf(s0[reg] - mnew) : 0.f;
        const float phi = okhi[reg] ? __expf(s1[reg] - mnew) : 0.f;
        rs += plo + phi;
        Psh[wave][lrow][4 * lgrp + reg] = f2bf(plo);
        Psh[wave][lrow][16 + 4 * lgrp + reg] = f2bf(phi);
      }
      rs += __shfl_xor(rs, 16);
      rs += __shfl_xor(rs, 32);
      l_l = l_l * sc + rs;
      m_l = mnew;

      // redistribute rescale factor to the O rows this lane holds (row = lgrp*4+reg)
      f32x4 scv;
#pragma unroll
      for (int reg = 0; reg < 4; ++reg) scv[reg] = __shfl(sc, lgrp * 4 + reg);
#pragma unroll
      for (int ch = 0; ch < 16; ++ch) Oacc[ch] *= scv;

      // ---- PV (Psh wave-private; wave-internal LDS ordering suffices) ----
      bf16x8 pa = *reinterpret_cast<const bf16x8*>(&Psh[wave][lrow][lgrp * 8]);
#pragma unroll
      for (int ch = 0; ch < 16; ++ch) {
        const ushort* vp = &Vsh[cur][(ch * 16 + lrow) * 36 + lgrp * 8];
        union { uint u[4]; bf16x8 v; } tmp;
        const uint2 lo = *reinterpret_cast<const uint2*>(vp);
        const uint2 hi = *reinterpret_cast<const uint2*>(vp + 4);
        tmp.u[0] = lo.x; tmp.u[1] = lo.y; tmp.u[2] = hi.x; tmp.u[3] = hi.y;
        Oacc[ch] = __builtin_amdgcn_mfma_f32_16x16x32_bf16(pa, tmp.v, Oacc[ch], 0, 0, 0);
      }

      if (pf) writeV(cur ^ 1, vpf);
      __syncthreads();
      cur ^= 1;
    }

    // ---- write bf16 output; fetch denom for O rows via shfl of l ----
    ushort* obase = O + ((size_t)b * S_ + q0 + wave * 16) * (NH_ * HD_) + (size_t)h * HD_;
#pragma unroll
    for (int reg = 0; reg < 4; ++reg) {
      const float lrow_l = __shfl(l_l, lgrp * 4 + reg);
      const float inv = 1.0f / lrow_l;
      ushort* orow = obase + (size_t)(lgrp * 4 + reg) * (NH_ * HD_);
#pragma unroll
      for (int ch = 0; ch < 16; ++ch)
        orow[ch * 16 + lrow] = f2bf(Oacc[ch][reg] * inv);
    }
  }
}

// ---------------- launch ----------------
extern "C" void kernel_launch(void* const* d_in, const int* in_sizes, int n_in,
                              void* d_out, int out_size, void* d_ws, size_t ws_size,
                              hipStream_t stream) {
  const float* hidden   = (const float*)d_in[0];
  const float* cos_t    = (const float*)d_in[1];
  const float* sin_t    = (const float*)d_in[2];
  const float* q_w      = (const float*)d_in[4];
  const float* k_w      = (const float*)d_in[5];
  const float* v_w      = (const float*)d_in[6];
  const float* o_w      = (const float*)d_in[7];
  const float* q_norm_w = (const float*)d_in[8];
  const float* k_norm_w = (const float*)d_in[9];
  float* out = (float*)d_out;

  char* ws = (char*)d_ws;
  ushort* hid_hi = (ushort*)(ws);                       // 16.78 MB
  ushort* hid_lo = (ushort*)(ws + 16777216);            // 16.78 MB, later v_proj
  ushort* wslot  = (ushort*)(ws + 33554432);            // 16.78 MB, reused per weight
  float*  q_slot = (float*)(ws + 50331648);             // 33.55 MB
  float*  k_slot = (float*)(ws + 83886080);             // 8.39 MB
  float*  v_slot = (float*)hid_lo;                      // overlay (hid_lo dead after k-gemm)
  ushort* attn_bf = hid_hi;                             // overlay (hid_hi dead after v-gemm)

  const int M = B_ * S_;  // 4096

  conv_split<<<2048, 256, 0, stream>>>(hidden, hid_hi, hid_lo, (B_ * S_ * HID_) / 4);

  // ---- Q projection (split) ----
  ushort* qw_hi = wslot;
  ushort* qw_lo = wslot + (size_t)NH_ * HD_ * HID_;
  conv_split<<<2048, 256, 0, stream>>>(q_w, qw_hi, qw_lo, (NH_ * HD_ * HID_) / 4);
  gemm_mfma<1><<<dim3((NH_ * HD_) / 128, M / 128), 256, 0, stream>>>(
      hid_hi, hid_lo, qw_hi, qw_lo, q_slot, M, NH_ * HD_, HID_);
  ln_rope_ip<<<M * NH_, 256, 0, stream>>>(q_slot, q_norm_w, cos_t, sin_t, NH_, 1, 1);

  // ---- K projection (split) ----
  ushort* kw_hi = wslot;
  ushort* kw_lo = wslot + (size_t)NKV_ * HD_ * HID_;
  conv_split<<<1024, 256, 0, stream>>>(k_w, kw_hi, kw_lo, (NKV_ * HD_ * HID_) / 4);
  gemm_mfma<1><<<dim3((NKV_ * HD_) / 128, M / 128), 256, 0, stream>>>(
      hid_hi, hid_lo, kw_hi, kw_lo, k_slot, M, NKV_ * HD_, HID_);
  ln_rope_ip<<<M * NKV_, 256, 0, stream>>>(k_slot, k_norm_w, cos_t, sin_t, NKV_, 1, 1);

  // ---- V projection (plain) ----
  ushort* vw_hi = wslot;
  conv_split<<<1024, 256, 0, stream>>>(v_w, vw_hi, nullptr, (NKV_ * HD_ * HID_) / 4);
  gemm_mfma<0><<<dim3((NKV_ * HD_) / 128, M / 128), 256, 0, stream>>>(
      hid_hi, nullptr, vw_hi, nullptr, v_slot, M, NKV_ * HD_, HID_);
  ln_rope_ip<<<M * NKV_, 256, 0, stream>>>(v_slot, nullptr, cos_t, sin_t, NKV_, 0, 0);

  // ---- attention: 256 balanced blocks (pair qi with 31-qi), 1 block/CU ----
  attn_mfma<<<dim3(16, NH_, B_), 256, 0, stream>>>(
      (const ushort*)q_slot, (const ushort*)k_slot, (const ushort*)v_slot, attn_bf);

  // ---- O projection (plain) ----
  ushort* ow_hi = wslot;
  conv_split<<<2048, 256, 0, stream>>>(o_w, ow_hi, nullptr, (HID_ * NH_ * HD_) / 4);
  gemm_mfma<0><<<dim3(HID_ / 128, M / 128), 256, 0, stream>>>(
      attn_bf, nullptr, ow_hi, nullptr, out, M, HID_, NH_ * HD_);
}